// Round 8
// baseline (80.761 us; speedup 1.0000x reference)
//
#include <hip/hip_runtime.h>
#include <hip/hip_bf16.h>

#define B_ 8
#define C_ 64
#define N_ 4096
#define K_ 20
#define T_ 3
#define O_ 64
#define P_ 20
#define NK_ (N_ * K_) /* 81920 */
#define BN_EPS 1e-5f

// workspace layout (float offsets)
#define WS_FEATT 0                           // B*N*C      = 2,097,152
#define WS_WT (WS_FEATT + B_ * N_ * C_)      // 245,760 f16 -> 122,880 float slots
#define WS_TAY (WS_WT + 122880)              // B*T*N*K    = 1,966,080
#define WS_RAW (WS_TAY + B_ * T_ * NK_)      // B*O*N      = 2,097,152
#define WS_PART (WS_RAW + B_ * O_ * N_)      // 512*64*2   =    65,536
#define WS_STATS (WS_PART + 512 * O_ * 2)    // 128

typedef __attribute__((ext_vector_type(8))) _Float16 half8;
typedef __attribute__((ext_vector_type(2))) _Float16 half2v;
typedef __attribute__((ext_vector_type(2))) __fp16 fp16x2;
typedef __attribute__((ext_vector_type(16))) float f32x16;

union UH8 {
    uint4 u;
    half8 h;
    half2v h2[4];
};
union UH2 {
    unsigned u;
    half2v h;
    fp16x2 f;
};

__device__ inline unsigned cvt_pkrtz_u(float a, float b) {
    UH2 x;
    x.f = __builtin_amdgcn_cvt_pkrtz(a, b);
    return x.u;
}

// K0: feat[b][c][n] -> featT[b][n][c]. XCD-aligned: linear block id %8 == b,
// matching k_main's consumer swizzle, so featT[b] lines land in XCD b's L2/L3 slice.
__global__ void k_transpose_feat(const float* __restrict__ feat, float* __restrict__ featT) {
    __shared__ float t[64][65];
    int bid = blockIdx.x;  // 512
    int b = bid & 7;
    int n0 = (bid >> 3) << 6;
    int lx = threadIdx.x & 63, ly = threadIdx.x >> 6;  // 256 threads
    const float* fp = feat + b * C_ * N_;
#pragma unroll
    for (int cc = 0; cc < 16; ++cc) {
        int c = ly * 16 + cc;
        t[c][lx] = fp[c * N_ + n0 + lx];
    }
    __syncthreads();
    float* op = featT + (b * N_ + n0) * C_;
#pragma unroll
    for (int u = 0; u < 16; ++u) {
        int n = ly * 16 + u;
        op[n * C_ + lx] = t[lx][n];
    }
}

// K5: pack conv_w into f16 MFMA A-fragment order.
// frag id = ((k*3+t)*4+cc)*2+oh ; within frag: lane l (o = oh*32+(l&31)),
// 8 f16 per lane: c = cc*16 + (l>>5)*8 + j
__global__ void k_pack_w(const float* __restrict__ cw, _Float16* __restrict__ Wh) {
    int e = blockIdx.x * 256 + threadIdx.x;  // 245760 total
    int j = e & 7;
    int l = (e >> 3) & 63;
    int frag = e >> 9;
    int oh = frag & 1;
    int cc = (frag >> 1) & 3;
    int kt = frag >> 3;
    int t = kt % 3, k = kt / 3;
    int o = oh * 32 + (l & 31);
    int c = cc * 16 + (l >> 5) * 8 + j;
    Wh[e] = (_Float16)cw[o * (C_ * T_ * K_) + (c * T_ + t) * K_ + k];
}

// K1: taylor, standalone (proven ~7us at 2560 blocks / high TLP).
// thread = flat b*NK + n*20+k -> weights reads perfectly coalesced.
// XCD-swizzled so batch b's stream+output stay on XCD b.
__global__ void k_taylor(const float* __restrict__ W5, const float* __restrict__ gpc,
                         float* __restrict__ tay) {
    int bid0 = blockIdx.x;  // 2560 = 8 * 320
    int bid = (bid0 & 7) * 320 + (bid0 >> 3);
    int tid = bid * 256 + threadIdx.x;
    int b = tid / NK_;
    int nk = tid - b * NK_;
    const float X = gpc[b * 3 * NK_ + nk];
    const float Y = gpc[b * 3 * NK_ + NK_ + nk];
    const float Z = gpc[b * 3 * NK_ + 2 * NK_ + nk];
    float XX = X * X, YY = Y * Y, ZZ = Z * Z;
    float XY = X * Y, XZ = X * Z, YZ = Y * Z;
    float terms[20];
    terms[0] = 1.f; terms[1] = X;      terms[2] = Y;       terms[3] = Z;
    terms[4] = XX;  terms[5] = YY;     terms[6] = ZZ;
    terms[7] = XX * X; terms[8] = YY * Y; terms[9] = ZZ * Z;
    terms[10] = XY; terms[11] = XZ;    terms[12] = YZ;
    terms[13] = X * XY;
    terms[14] = X * XZ;
    terms[15] = Y * YZ;
    terms[16] = Y * XY;
    terms[17] = Z * XZ;
    terms[18] = Z * YZ;
    terms[19] = XY * Z;
    float a0 = 0.f, a1 = 0.f, a2 = 0.f;
    const float* wp = W5 + (size_t)b * P_ * T_ * NK_ + nk;
#pragma unroll
    for (int p = 0; p < P_; ++p) {
        float tp = terms[p];
        a0 += wp[0] * tp;
        a1 += wp[NK_] * tp;
        a2 += wp[2 * NK_] * tp;
        wp += 3 * NK_;
    }
    float* tp = tay + (size_t)b * T_ * NK_ + nk;
    tp[0] = a0;
    tp[NK_] = a1;
    tp[2 * NK_] = a2;
}

// K2: main contraction via f16 MFMA 32x32x16.
// Block = (b, 64-n tile), 512 threads = 8 waves (wc = c-slice, wo = o-half).
// 3-deep LDS pipeline: gathers issued ~2.3 iterations before use (covers L3
// latency); G tile stored as f16 (staging threads convert; no cvt in MFMA path).
// Exactly 1 barrier per k-iteration.
__global__ __launch_bounds__(512, 4) void k_main(const float* __restrict__ featT,
                                                 const _Float16* __restrict__ Wh,
                                                 const float* __restrict__ tay,
                                                 const int* __restrict__ idx,
                                                 float* __restrict__ raw,
                                                 float* __restrict__ part) {
    __shared__ unsigned short Gh[3][64][72];  // f16 bits, 27,648 B; pad 72 -> 2-way reads
    __shared__ union {
        struct {
            unsigned tayH[T_][K_][64];  // 15,360 B : half2(tay,tay)
            int idxS[K_][64];           //  5,120 B
        } s;
        float out[64][68];  // 17,408 B epilogue merge buffer
    } su;

    // XCD-aware bijective swizzle (512 blocks, 8 XCDs): XCD = bid0%8 = b
    const int bid0 = blockIdx.x;
    const int bid = (bid0 & 7) * 64 + (bid0 >> 3);
    const int b = bid >> 6;
    const int n0 = (bid & 63) << 6;
    const int tid = threadIdx.x;
    const int lane = tid & 63;
    const int wv = tid >> 6;  // 0..7
    const int wc = wv & 3;    // c-slice 16*wc
    const int wo = wv >> 2;   // o-half 32*wo
    const int nl = lane & 31;
    const int kf = lane >> 5;

    {  // stage idx (coalesced)
        const int* ip = idx + (b * N_ + n0) * K_;
        for (int e = tid; e < 64 * K_; e += 512) su.s.idxS[e % K_][e / K_] = ip[e];
    }
    {  // stage tay -> f16 pairs
#pragma unroll
        for (int t = 0; t < 3; ++t) {
            const float* tp = tay + ((size_t)(b * 3 + t) * N_ + n0) * K_;
            for (int e = tid; e < 64 * K_; e += 512) {
                float v = tp[e];
                su.s.tayH[t][e % K_][e / K_] = cvt_pkrtz_u(v, v);
            }
        }
    }
    __syncthreads();

    f32x16 acc[2];
#pragma unroll
    for (int nh = 0; nh < 2; ++nh)
#pragma unroll
        for (int i = 0; i < 16; ++i) acc[nh][i] = 0.f;

    const float* fb = featT + (size_t)b * N_ * C_;
    // staging: thread covers rows r1 = tid>>4 (0..31) and r1+32, 4-float segment sseg
    const int r1 = tid >> 4, r2 = r1 + 32, sseg = tid & 15;

    // prologue: prefetch k = 0,1,2 (16-lane contiguous 256B runs per row)
    float4 stA[3], stB[3];
#pragma unroll
    for (int j = 0; j < 3; ++j) {
        stA[j] = *(const float4*)(fb + su.s.idxS[j][r1] * C_ + sseg * 4);
        stB[j] = *(const float4*)(fb + su.s.idxS[j][r2] * C_ + sseg * 4);
    }

#pragma unroll
    for (int k = 0; k < K_; ++k) {
        const int buf = k % 3;  // static after unroll
        uint2 wA, wB;
        wA.x = cvt_pkrtz_u(stA[buf].x, stA[buf].y);
        wA.y = cvt_pkrtz_u(stA[buf].z, stA[buf].w);
        wB.x = cvt_pkrtz_u(stB[buf].x, stB[buf].y);
        wB.y = cvt_pkrtz_u(stB[buf].z, stB[buf].w);
        *(uint2*)&Gh[buf][r1][sseg * 4] = wA;
        *(uint2*)&Gh[buf][r2][sseg * 4] = wB;
        __syncthreads();  // buf published; safe: all compute <= k-2 finished
        if (k + 3 < K_) {  // refill this buffer's regs; ~2.3 iters until needed
            stA[buf] = *(const float4*)(fb + su.s.idxS[k + 3][r1] * C_ + sseg * 4);
            stB[buf] = *(const float4*)(fb + su.s.idxS[k + 3][r2] * C_ + sseg * 4);
        }
        UH8 g0, g1;
        g0.u = *(const uint4*)&Gh[buf][nl][wc * 16 + kf * 8];
        g1.u = *(const uint4*)&Gh[buf][nl + 32][wc * 16 + kf * 8];
#pragma unroll
        for (int t = 0; t < 3; ++t) {
            UH8 ar;
            ar.u = *(const uint4*)(Wh +
                                   (size_t)((((k * 3 + t) * 4 + wc) * 2 + wo) * 64 + lane) * 8);
            UH2 tv0, tv1;
            tv0.u = su.s.tayH[t][k][nl];
            tv1.u = su.s.tayH[t][k][nl + 32];
            UH8 b0, b1;
#pragma unroll
            for (int i = 0; i < 4; ++i) {
                b0.h2[i] = g0.h2[i] * tv0.h;  // v_pk_mul_f16
                b1.h2[i] = g1.h2[i] * tv1.h;
            }
            acc[0] = __builtin_amdgcn_mfma_f32_32x32x16_f16(ar.h, b0.h, acc[0], 0, 0, 0);
            acc[1] = __builtin_amdgcn_mfma_f32_32x32x16_f16(ar.h, b1.h, acc[1], 0, 0, 0);
        }
    }

    __syncthreads();  // all LDS reads of su.s done; su.out overlays it
    // serialized cross-wave c-merge (deterministic); wo halves are disjoint rows
#pragma unroll 1
    for (int ww = 0; ww < 4; ++ww) {
        if (wc == ww) {
#pragma unroll
            for (int nh = 0; nh < 2; ++nh)
#pragma unroll
                for (int r = 0; r < 16; ++r) {
                    int row = wo * 32 + (r & 3) + ((r >> 2) << 3) + (kf << 2);
                    int col = nh * 32 + nl;
                    if (ww == 0)
                        su.out[row][col] = acc[nh][r];
                    else
                        su.out[row][col] += acc[nh][r];
                }
        }
        __syncthreads();
    }

    if (tid < 256) {  // write raw tile, coalesced float4
        int o = tid >> 2, seg = tid & 3;
        float4* dst = (float4*)(raw + ((b * O_ + o) * N_) + n0 + seg * 16);
        const float* srow = &su.out[o][seg * 16];
        dst[0] = *(const float4*)&srow[0];
        dst[1] = *(const float4*)&srow[4];
        dst[2] = *(const float4*)&srow[8];
        dst[3] = *(const float4*)&srow[12];
    }
    if (tid < 64) {  // per-block BN partial sums
        float s1 = 0.f, s2 = 0.f;
#pragma unroll 8
        for (int n = 0; n < 64; ++n) {
            float v = su.out[tid][n];
            s1 += v;
            s2 += v * v;
        }
        part[(bid * 64 + tid) * 2 + 0] = s1;
        part[(bid * 64 + tid) * 2 + 1] = s2;
    }
}

// K3: reduce 512 block-partials per channel -> scale/shift (deterministic)
__global__ void k_bnstats(const float* __restrict__ part, const float* __restrict__ gamma,
                          const float* __restrict__ beta, float* __restrict__ stats) {
    int o = blockIdx.x;
    int tid = threadIdx.x;
    __shared__ float s1s[256], s2s[256];
    float s1 = 0.f, s2 = 0.f;
    for (int j = tid; j < 512; j += 256) {
        s1 += part[(j * 64 + o) * 2 + 0];
        s2 += part[(j * 64 + o) * 2 + 1];
    }
    s1s[tid] = s1;
    s2s[tid] = s2;
    __syncthreads();
    for (int s = 128; s > 0; s >>= 1) {
        if (tid < s) {
            s1s[tid] += s1s[tid + s];
            s2s[tid] += s2s[tid + s];
        }
        __syncthreads();
    }
    if (tid == 0) {
        const float cnt = (float)(B_ * N_);
        float mean = s1s[0] / cnt;
        float var = s2s[0] / cnt - mean * mean;
        float sc = gamma[o] * rsqrtf(var + BN_EPS);
        stats[o * 2 + 0] = sc;
        stats[o * 2 + 1] = beta[o] - mean * sc;
    }
}

// K4: normalize + ReLU, float4
__global__ void k_finalize(const float* __restrict__ raw, const float* __restrict__ stats,
                           float* __restrict__ out) {
    int e = (blockIdx.x * 256 + threadIdx.x) * 4;
    int o = (e >> 12) & 63;
    float sc = stats[o * 2 + 0], sh = stats[o * 2 + 1];
    float4 v = *(const float4*)(raw + e);
    v.x = fmaxf(v.x * sc + sh, 0.f);
    v.y = fmaxf(v.y * sc + sh, 0.f);
    v.z = fmaxf(v.z * sc + sh, 0.f);
    v.w = fmaxf(v.w * sc + sh, 0.f);
    *(float4*)(out + e) = v;
}

extern "C" void kernel_launch(void* const* d_in, const int* in_sizes, int n_in,
                              void* d_out, int out_size, void* d_ws, size_t ws_size,
                              hipStream_t stream) {
    const float* feat = (const float*)d_in[0];
    const int* idx = (const int*)d_in[1];
    const float* gpc = (const float*)d_in[2];
    const float* weights = (const float*)d_in[3];
    const float* conv_w = (const float*)d_in[4];
    const float* gamma = (const float*)d_in[5];
    const float* beta = (const float*)d_in[6];
    float* out = (float*)d_out;
    float* ws = (float*)d_ws;

    float* featT = ws + WS_FEATT;
    _Float16* Wh = (_Float16*)(ws + WS_WT);
    float* tay = ws + WS_TAY;
    float* raw = ws + WS_RAW;
    float* part = ws + WS_PART;
    float* stats = ws + WS_STATS;

    hipLaunchKernelGGL(k_transpose_feat, dim3(512), dim3(256), 0, stream, feat, featT);
    hipLaunchKernelGGL(k_pack_w, dim3((K_ * T_ * C_ * O_) / 256), dim3(256), 0, stream, conv_w,
                       Wh);
    hipLaunchKernelGGL(k_taylor, dim3(B_ * NK_ / 256), dim3(256), 0, stream, weights, gpc, tay);
    hipLaunchKernelGGL(k_main, dim3(B_ * (N_ / 64)), dim3(512), 0, stream, featT, Wh, tay, idx,
                       raw, part);
    hipLaunchKernelGGL(k_bnstats, dim3(O_), dim3(256), 0, stream, part, gamma, beta, stats);
    hipLaunchKernelGGL(k_finalize, dim3(B_ * O_ * N_ / 4 / 256), dim3(256), 0, stream, raw, stats,
                       out);
}

// Round 9
// 78.219 us; speedup vs baseline: 1.0325x; 1.0325x over previous
//
#include <hip/hip_runtime.h>
#include <hip/hip_bf16.h>

#define B_ 8
#define C_ 64
#define N_ 4096
#define K_ 20
#define T_ 3
#define O_ 64
#define P_ 20
#define NK_ (N_ * K_) /* 81920 */
#define BN_EPS 1e-5f

// workspace layout (float offsets)
#define WS_FEATT 0                           // B*N*C      = 2,097,152
#define WS_WT (WS_FEATT + B_ * N_ * C_)      // 245,760 f16 -> 122,880 float slots
#define WS_RAW (WS_WT + 122880)              // B*O*N      = 2,097,152
#define WS_PART (WS_RAW + B_ * O_ * N_)      // 1024*64*2  =   131,072
#define WS_STATS (WS_PART + 131072)          // 128

typedef __attribute__((ext_vector_type(8))) _Float16 half8;
typedef __attribute__((ext_vector_type(2))) _Float16 half2v;
typedef __attribute__((ext_vector_type(2))) __fp16 fp16x2;
typedef __attribute__((ext_vector_type(16))) float f32x16;

union UH8 {
    uint4 u;
    half8 h;
    half2v h2[4];
};
union UH2 {
    unsigned u;
    half2v h;
    fp16x2 f;
};

__device__ inline unsigned cvt_pkrtz_u(float a, float b) {
    UH2 x;
    x.f = __builtin_amdgcn_cvt_pkrtz(a, b);
    return x.u;
}

// K0: feat[b][c][n] -> featT[b][n][c]. XCD-aligned: linear block id %8 == b,
// matching k_main's consumer swizzle, so featT[b] lines live on XCD b's L2.
__global__ void k_transpose_feat(const float* __restrict__ feat, float* __restrict__ featT) {
    __shared__ float t[64][65];
    int bid = blockIdx.x;  // 512
    int b = bid & 7;
    int n0 = (bid >> 3) << 6;
    int lx = threadIdx.x & 63, ly = threadIdx.x >> 6;  // 256 threads
    const float* fp = feat + b * C_ * N_;
#pragma unroll
    for (int cc = 0; cc < 16; ++cc) {
        int c = ly * 16 + cc;
        t[c][lx] = fp[c * N_ + n0 + lx];
    }
    __syncthreads();
    float* op = featT + (b * N_ + n0) * C_;
#pragma unroll
    for (int u = 0; u < 16; ++u) {
        int n = ly * 16 + u;
        op[n * C_ + lx] = t[lx][n];
    }
}

// K5: pack conv_w into f16 MFMA A-fragment order.
// frag id = ((k*3+t)*4+cc)*2+oh ; within frag: lane l (o = oh*32+(l&31)),
// 8 f16 per lane: c = cc*16 + (l>>5)*8 + j
__global__ void k_pack_w(const float* __restrict__ cw, _Float16* __restrict__ Wh) {
    int e = blockIdx.x * 256 + threadIdx.x;  // 245760 total
    int j = e & 7;
    int l = (e >> 3) & 63;
    int frag = e >> 9;
    int oh = frag & 1;
    int cc = (frag >> 1) & 3;
    int kt = frag >> 3;
    int t = kt % 3, k = kt / 3;
    int o = oh * 32 + (l & 31);
    int c = cc * 16 + (l >> 5) * 8 + j;
    Wh[e] = (_Float16)cw[o * (C_ * T_ * K_) + (c * T_ + t) * K_ + k];
}

// K2: fused taylor + main contraction, f16 MFMA 32x32x16.
// Block = (b, 32-n tile): grid 1024 = 4 blocks/CU, 512 thr = 8 waves ->
// 32 waves/CU (100% occupancy) to hide gather/stream latency.
// Wave wv: wc = wv&3 (c-slice), wo = wv>>2 (o-half). One 32n-frag per wave.
__global__ __launch_bounds__(512, 8) void k_main(const float* __restrict__ featT,
                                                 const _Float16* __restrict__ Wh,
                                                 const float* __restrict__ weights,
                                                 const float* __restrict__ gpc,
                                                 const int* __restrict__ idx,
                                                 float* __restrict__ raw,
                                                 float* __restrict__ part) {
    __shared__ unsigned short Gh[2][32][72];  // f16 gather tile, 9,216 B
    __shared__ union {
        struct {
            unsigned tayH[T_][K_][32];  // 7,680 B : half2(tay,tay)
            int idxS[K_][32];           // 2,560 B
        } s;
        float out[64][36];  // 9,216 B epilogue merge buffer (o rows, n cols)
    } su;  // 10,240 B -> total LDS ~19.5 KB -> 4 blocks/CU

    // XCD-aware bijective swizzle (1024 blocks, 8 XCDs): XCD = bid0%8 = b
    const int bid0 = blockIdx.x;
    const int bid = (bid0 & 7) * 128 + (bid0 >> 3);
    const int b = bid >> 7;
    const int n0 = (bid & 127) << 5;
    const int tid = threadIdx.x;
    const int lane = tid & 63;
    const int wv = tid >> 6;  // 0..7
    const int wc = wv & 3;    // c-slice 16*wc
    const int wo = wv >> 2;   // o-half 32*wo
    const int nl = lane & 31;
    const int kf = lane >> 5;

    {  // stage idx (coalesced; 640 entries)
        const int* ip = idx + (b * N_ + n0) * K_;
        for (int e = tid; e < 32 * K_; e += 512) su.s.idxS[e % K_][e / K_] = ip[e];
    }
    {  // fused taylor for this block's 32-n slice: e = n*20+k matches memory
       // order -> gpc/weights reads perfectly coalesced across the thread front
        const float* gpcb = gpc + (size_t)b * 3 * NK_ + n0 * K_;
        const float* wb0 = weights + (size_t)b * P_ * T_ * NK_ + n0 * K_;
        for (int e = tid; e < 32 * K_; e += 512) {
            float X = gpcb[e];
            float Y = gpcb[NK_ + e];
            float Z = gpcb[2 * NK_ + e];
            float XX = X * X, YY = Y * Y, ZZ = Z * Z;
            float XY = X * Y, XZ = X * Z, YZ = Y * Z;
            float terms[20];
            terms[0] = 1.f; terms[1] = X;      terms[2] = Y;       terms[3] = Z;
            terms[4] = XX;  terms[5] = YY;     terms[6] = ZZ;
            terms[7] = XX * X; terms[8] = YY * Y; terms[9] = ZZ * Z;
            terms[10] = XY; terms[11] = XZ;    terms[12] = YZ;
            terms[13] = X * XY;
            terms[14] = X * XZ;
            terms[15] = Y * YZ;
            terms[16] = Y * XY;
            terms[17] = Z * XZ;
            terms[18] = Z * YZ;
            terms[19] = XY * Z;
            float a0 = 0.f, a1 = 0.f, a2 = 0.f;
            const float* wp = wb0 + e;
#pragma unroll
            for (int p = 0; p < P_; ++p) {
                float tp = terms[p];
                a0 += wp[0] * tp;
                a1 += wp[(size_t)NK_] * tp;
                a2 += wp[2 * (size_t)NK_] * tp;
                wp += 3 * (size_t)NK_;
            }
            int n = e / K_, k = e - (e / K_) * K_;
            su.s.tayH[0][k][n] = cvt_pkrtz_u(a0, a0);
            su.s.tayH[1][k][n] = cvt_pkrtz_u(a1, a1);
            su.s.tayH[2][k][n] = cvt_pkrtz_u(a2, a2);
        }
    }
    __syncthreads();

    f32x16 acc;
#pragma unroll
    for (int i = 0; i < 16; ++i) acc[i] = 0.f;

    const float* fb = featT + (size_t)b * N_ * C_;
    // staging: thread covers row r = tid>>4 (0..31), 16B segment sseg = tid&15
    const int r = tid >> 4, sseg = tid & 15;

    // prologue: k=0 gather (16-lane contiguous 256B runs per row)
    float4 st = *(const float4*)(fb + su.s.idxS[0][r] * C_ + sseg * 4);

    for (int k = 0; k < K_; ++k) {
        const int buf = k & 1;
        uint2 w;
        w.x = cvt_pkrtz_u(st.x, st.y);
        w.y = cvt_pkrtz_u(st.z, st.w);
        *(uint2*)&Gh[buf][r][sseg * 4] = w;
        __syncthreads();  // buf published; prior readers of buf done at k-1's barrier
        if (k + 1 < K_) {  // next gather flies under this iter's compute
            st = *(const float4*)(fb + su.s.idxS[k + 1][r] * C_ + sseg * 4);
        }
        UH8 g;
        g.u = *(const uint4*)&Gh[buf][nl][wc * 16 + kf * 8];
#pragma unroll
        for (int t = 0; t < 3; ++t) {
            UH8 ar;
            ar.u = *(const uint4*)(Wh +
                                   (size_t)((((k * 3 + t) * 4 + wc) * 2 + wo) * 64 + lane) * 8);
            UH2 tv;
            tv.u = su.s.tayH[t][k][nl];
            UH8 bv;
#pragma unroll
            for (int i = 0; i < 4; ++i) bv.h2[i] = g.h2[i] * tv.h;  // v_pk_mul_f16
            acc = __builtin_amdgcn_mfma_f32_32x32x16_f16(ar.h, bv.h, acc, 0, 0, 0);
        }
    }

    __syncthreads();  // all LDS reads of su.s done; su.out overlays it
    // serialized cross-wave c-merge (deterministic); wo halves are disjoint rows
#pragma unroll 1
    for (int ww = 0; ww < 4; ++ww) {
        if (wc == ww) {
#pragma unroll
            for (int rr = 0; rr < 16; ++rr) {
                int row = wo * 32 + (rr & 3) + ((rr >> 2) << 3) + (kf << 2);
                if (ww == 0)
                    su.out[row][nl] = acc[rr];
                else
                    su.out[row][nl] += acc[rr];
            }
        }
        __syncthreads();
    }

    {  // write raw tile: 512 threads, o = tid>>3, 4-float segment seg = tid&7
        int o = tid >> 3, seg = tid & 7;
        float4* dst = (float4*)(raw + ((b * O_ + o) * N_) + n0 + seg * 4);
        const float* srow = &su.out[o][seg * 4];
        *dst = make_float4(srow[0], srow[1], srow[2], srow[3]);
    }
    if (tid < 64) {  // per-block BN partial sums over 32 n
        float s1 = 0.f, s2 = 0.f;
#pragma unroll 8
        for (int n = 0; n < 32; ++n) {
            float v = su.out[tid][n];
            s1 += v;
            s2 += v * v;
        }
        part[(bid * 64 + tid) * 2 + 0] = s1;
        part[(bid * 64 + tid) * 2 + 1] = s2;
    }
}

// K3: reduce 1024 block-partials per channel -> scale/shift (deterministic)
__global__ void k_bnstats(const float* __restrict__ part, const float* __restrict__ gamma,
                          const float* __restrict__ beta, float* __restrict__ stats) {
    int o = blockIdx.x;
    int tid = threadIdx.x;
    __shared__ float s1s[256], s2s[256];
    float s1 = 0.f, s2 = 0.f;
    for (int j = tid; j < 1024; j += 256) {
        s1 += part[(j * 64 + o) * 2 + 0];
        s2 += part[(j * 64 + o) * 2 + 1];
    }
    s1s[tid] = s1;
    s2s[tid] = s2;
    __syncthreads();
    for (int s = 128; s > 0; s >>= 1) {
        if (tid < s) {
            s1s[tid] += s1s[tid + s];
            s2s[tid] += s2s[tid + s];
        }
        __syncthreads();
    }
    if (tid == 0) {
        const float cnt = (float)(B_ * N_);
        float mean = s1s[0] / cnt;
        float var = s2s[0] / cnt - mean * mean;
        float sc = gamma[o] * rsqrtf(var + BN_EPS);
        stats[o * 2 + 0] = sc;
        stats[o * 2 + 1] = beta[o] - mean * sc;
    }
}

// K4: normalize + ReLU, float4
__global__ void k_finalize(const float* __restrict__ raw, const float* __restrict__ stats,
                           float* __restrict__ out) {
    int e = (blockIdx.x * 256 + threadIdx.x) * 4;
    int o = (e >> 12) & 63;
    float sc = stats[o * 2 + 0], sh = stats[o * 2 + 1];
    float4 v = *(const float4*)(raw + e);
    v.x = fmaxf(v.x * sc + sh, 0.f);
    v.y = fmaxf(v.y * sc + sh, 0.f);
    v.z = fmaxf(v.z * sc + sh, 0.f);
    v.w = fmaxf(v.w * sc + sh, 0.f);
    *(float4*)(out + e) = v;
}

extern "C" void kernel_launch(void* const* d_in, const int* in_sizes, int n_in,
                              void* d_out, int out_size, void* d_ws, size_t ws_size,
                              hipStream_t stream) {
    const float* feat = (const float*)d_in[0];
    const int* idx = (const int*)d_in[1];
    const float* gpc = (const float*)d_in[2];
    const float* weights = (const float*)d_in[3];
    const float* conv_w = (const float*)d_in[4];
    const float* gamma = (const float*)d_in[5];
    const float* beta = (const float*)d_in[6];
    float* out = (float*)d_out;
    float* ws = (float*)d_ws;

    float* featT = ws + WS_FEATT;
    _Float16* Wh = (_Float16*)(ws + WS_WT);
    float* raw = ws + WS_RAW;
    float* part = ws + WS_PART;
    float* stats = ws + WS_STATS;

    hipLaunchKernelGGL(k_transpose_feat, dim3(512), dim3(256), 0, stream, feat, featT);
    hipLaunchKernelGGL(k_pack_w, dim3((K_ * T_ * C_ * O_) / 256), dim3(256), 0, stream, conv_w,
                       Wh);
    hipLaunchKernelGGL(k_main, dim3(B_ * (N_ / 32)), dim3(512), 0, stream, featT, Wh, weights,
                       gpc, idx, raw, part);
    hipLaunchKernelGGL(k_bnstats, dim3(O_), dim3(256), 0, stream, part, gamma, beta, stats);
    hipLaunchKernelGGL(k_finalize, dim3(B_ * O_ * N_ / 4 / 256), dim3(256), 0, stream, raw, stats,
                       out);
}

// Round 10
// 70.671 us; speedup vs baseline: 1.1428x; 1.1068x over previous
//
#include <hip/hip_runtime.h>
#include <hip/hip_bf16.h>

#define B_ 8
#define C_ 64
#define N_ 4096
#define K_ 20
#define T_ 3
#define O_ 64
#define P_ 20
#define NK_ (N_ * K_) /* 81920 */
#define BN_EPS 1e-5f
#define KG 5  /* k-slices per staged phase */

// workspace layout (float offsets)
#define WS_FEATT 0                           // B*N*C      = 2,097,152
#define WS_WT (WS_FEATT + B_ * N_ * C_)      // 245,760 f16 -> 122,880 float slots
#define WS_RAW (WS_WT + 122880)              // B*O*N      = 2,097,152
#define WS_PART (WS_RAW + B_ * O_ * N_)      // 1024*64*2  =   131,072
#define WS_STATS (WS_PART + 131072)          // 128

typedef __attribute__((ext_vector_type(8))) _Float16 half8;
typedef __attribute__((ext_vector_type(2))) _Float16 half2v;
typedef __attribute__((ext_vector_type(2))) __fp16 fp16x2;
typedef __attribute__((ext_vector_type(16))) float f32x16;

union UH8 {
    uint4 u;
    half8 h;
    half2v h2[4];
};
union UH2 {
    unsigned u;
    half2v h;
    fp16x2 f;
};

__device__ inline unsigned cvt_pkrtz_u(float a, float b) {
    UH2 x;
    x.f = __builtin_amdgcn_cvt_pkrtz(a, b);
    return x.u;
}

// K0: feat[b][c][n] -> featT[b][n][c]. XCD-aligned with k_main's consumer swizzle.
__global__ void k_transpose_feat(const float* __restrict__ feat, float* __restrict__ featT) {
    __shared__ float t[64][65];
    int bid = blockIdx.x;  // 512
    int b = bid & 7;
    int n0 = (bid >> 3) << 6;
    int lx = threadIdx.x & 63, ly = threadIdx.x >> 6;  // 256 threads
    const float* fp = feat + b * C_ * N_;
#pragma unroll
    for (int cc = 0; cc < 16; ++cc) {
        int c = ly * 16 + cc;
        t[c][lx] = fp[c * N_ + n0 + lx];
    }
    __syncthreads();
    float* op = featT + (b * N_ + n0) * C_;
#pragma unroll
    for (int u = 0; u < 16; ++u) {
        int n = ly * 16 + u;
        op[n * C_ + lx] = t[lx][n];
    }
}

// K5: pack conv_w into f16 MFMA A-fragment order.
__global__ void k_pack_w(const float* __restrict__ cw, _Float16* __restrict__ Wh) {
    int e = blockIdx.x * 256 + threadIdx.x;  // 245760 total
    int j = e & 7;
    int l = (e >> 3) & 63;
    int frag = e >> 9;
    int oh = frag & 1;
    int cc = (frag >> 1) & 3;
    int kt = frag >> 3;
    int t = kt % 3, k = kt / 3;
    int o = oh * 32 + (l & 31);
    int c = cc * 16 + (l >> 5) * 8 + j;
    Wh[e] = (_Float16)cw[o * (C_ * T_ * K_) + (c * T_ + t) * K_ + k];
}

// K2: fused taylor + phase-batched MFMA contraction.
// Block = (b, 32-n tile), 512 thr = 8 waves (wc = c-slice, wo = o-half).
// k is processed in 4 phases of KG=5; E tile double-buffered in LDS; each
// thread issues 5 independent gathers a full phase ahead (4 barriers total).
__global__ __launch_bounds__(512, 4) void k_main(const float* __restrict__ featT,
                                                 const _Float16* __restrict__ Wh,
                                                 const float* __restrict__ weights,
                                                 const float* __restrict__ gpc,
                                                 const int* __restrict__ idx,
                                                 float* __restrict__ raw,
                                                 float* __restrict__ part) {
    __shared__ unsigned short E[2][KG][32][68];  // f16, 43,520 B; pad 68 -> 2-way reads
    __shared__ union {
        unsigned tayH[T_][K_][32];  // 7,680 B : half2(tay,tay)
        float out[64][36];          // 9,216 B epilogue merge buffer
    } su;

    // XCD-aware bijective swizzle (1024 blocks, 8 XCDs): XCD = bid0%8 = b
    const int bid0 = blockIdx.x;
    const int bid = (bid0 & 7) * 128 + (bid0 >> 3);
    const int b = bid >> 7;
    const int n0 = (bid & 127) << 5;
    const int tid = threadIdx.x;
    const int lane = tid & 63;
    const int wv = tid >> 6;
    const int wc = wv & 3;    // c-slice 16*wc
    const int wo = wv >> 2;   // o-half 32*wo
    const int nl = lane & 31;
    const int kf = lane >> 5;
    const int row = tid >> 4, seg = tid & 15;  // staging: (gather row, 16B segment)

    const float* fb = featT + (size_t)b * N_ * C_;

    // --- read this row's 20 idx values into registers (16 threads/row broadcast)
    int idxv[K_];
    {
        const int4* ip4 = (const int4*)(idx + (size_t)(b * N_ + n0 + row) * K_);
#pragma unroll
        for (int q = 0; q < 5; ++q) {
            int4 v = ip4[q];
            idxv[q * 4 + 0] = v.x;
            idxv[q * 4 + 1] = v.y;
            idxv[q * 4 + 2] = v.z;
            idxv[q * 4 + 3] = v.w;
        }
    }

    // --- issue phase-0 gathers immediately (fly under the taylor stream)
    float4 gA[KG], gB[KG];
#pragma unroll
    for (int kk = 0; kk < KG; ++kk)
        gA[kk] = *(const float4*)(fb + (size_t)idxv[kk] * C_ + seg * 4);

    // --- fused taylor for this block's 32-n slice (coalesced weights stream)
    {
        const float* gpcb = gpc + (size_t)b * 3 * NK_ + n0 * K_;
        const float* wb0 = weights + (size_t)b * P_ * T_ * NK_ + n0 * K_;
        for (int e = tid; e < 32 * K_; e += 512) {
            float X = gpcb[e];
            float Y = gpcb[NK_ + e];
            float Z = gpcb[2 * NK_ + e];
            float XX = X * X, YY = Y * Y, ZZ = Z * Z;
            float XY = X * Y, XZ = X * Z, YZ = Y * Z;
            float terms[20];
            terms[0] = 1.f; terms[1] = X;      terms[2] = Y;       terms[3] = Z;
            terms[4] = XX;  terms[5] = YY;     terms[6] = ZZ;
            terms[7] = XX * X; terms[8] = YY * Y; terms[9] = ZZ * Z;
            terms[10] = XY; terms[11] = XZ;    terms[12] = YZ;
            terms[13] = X * XY;
            terms[14] = X * XZ;
            terms[15] = Y * YZ;
            terms[16] = Y * XY;
            terms[17] = Z * XZ;
            terms[18] = Z * YZ;
            terms[19] = XY * Z;
            float a0 = 0.f, a1 = 0.f, a2 = 0.f;
            const float* wp = wb0 + e;
#pragma unroll
            for (int p = 0; p < P_; ++p) {
                float tp = terms[p];
                a0 += wp[0] * tp;
                a1 += wp[(size_t)NK_] * tp;
                a2 += wp[2 * (size_t)NK_] * tp;
                wp += 3 * (size_t)NK_;
            }
            int n = e / K_, k = e - n * K_;
            su.tayH[0][k][n] = cvt_pkrtz_u(a0, a0);
            su.tayH[1][k][n] = cvt_pkrtz_u(a1, a1);
            su.tayH[2][k][n] = cvt_pkrtz_u(a2, a2);
        }
    }

    // --- write E[0] from phase-0 gathers; issue phase-1 gathers
#pragma unroll
    for (int kk = 0; kk < KG; ++kk) {
        uint2 w;
        w.x = cvt_pkrtz_u(gA[kk].x, gA[kk].y);
        w.y = cvt_pkrtz_u(gA[kk].z, gA[kk].w);
        *(uint2*)&E[0][kk][row][seg * 4] = w;
    }
#pragma unroll
    for (int kk = 0; kk < KG; ++kk)
        gA[kk] = *(const float4*)(fb + (size_t)idxv[KG + kk] * C_ + seg * 4);
    __syncthreads();

    f32x16 acc;
#pragma unroll
    for (int i = 0; i < 16; ++i) acc[i] = 0.f;

    // --- 4 phases; per phase: [issue p+2 loads][compute p][write p+1][barrier]
#pragma unroll
    for (int p = 0; p < 4; ++p) {
        // issue loads for phase p+2 into the spare register set
        if (p + 2 < 4) {
#pragma unroll
            for (int kk = 0; kk < KG; ++kk) {
                float4 v = *(const float4*)(fb + (size_t)idxv[(p + 2) * KG + kk] * C_ + seg * 4);
                if (p & 1) gA[kk] = v; else gB[kk] = v;
            }
        }
        // compute phase p from E[p&1]
#pragma unroll
        for (int kk = 0; kk < KG; ++kk) {
            UH8 gv;
            gv.u = *(const uint4*)&E[p & 1][kk][nl][wc * 16 + kf * 8];
            const int k = p * KG + kk;
#pragma unroll
            for (int t = 0; t < 3; ++t) {
                UH8 ar;
                ar.u = *(const uint4*)(Wh +
                                       (size_t)((((k * 3 + t) * 4 + wc) * 2 + wo) * 64 + lane) * 8);
                UH2 tv;
                tv.u = su.tayH[t][k][nl];
                UH8 bv;
#pragma unroll
                for (int i = 0; i < 4; ++i) bv.h2[i] = gv.h2[i] * tv.h;  // v_pk_mul_f16
                acc = __builtin_amdgcn_mfma_f32_32x32x16_f16(ar.h, bv.h, acc, 0, 0, 0);
            }
        }
        // write E[(p+1)&1] from loads issued at phase p-1 (safe: barrier p-1
        // guarantees all waves finished compute p-1, the prior reader of this buf)
        if (p + 1 < 4) {
#pragma unroll
            for (int kk = 0; kk < KG; ++kk) {
                float4 v = (p & 1) ? gB[kk] : gA[kk];
                uint2 w;
                w.x = cvt_pkrtz_u(v.x, v.y);
                w.y = cvt_pkrtz_u(v.z, v.w);
                *(uint2*)&E[(p + 1) & 1][kk][row][seg * 4] = w;
            }
        }
        __syncthreads();
    }

    // --- serialized cross-wave c-merge (deterministic); su.out overlays tayH
#pragma unroll 1
    for (int ww = 0; ww < 4; ++ww) {
        if (wc == ww) {
#pragma unroll
            for (int rr = 0; rr < 16; ++rr) {
                int orow = wo * 32 + (rr & 3) + ((rr >> 2) << 3) + (kf << 2);
                if (ww == 0)
                    su.out[orow][nl] = acc[rr];
                else
                    su.out[orow][nl] += acc[rr];
            }
        }
        __syncthreads();
    }

    {  // write raw tile: o = tid>>3, 4-float segment
        int o = tid >> 3, sg = tid & 7;
        float4* dst = (float4*)(raw + ((b * O_ + o) * N_) + n0 + sg * 4);
        const float* srow = &su.out[o][sg * 4];
        *dst = make_float4(srow[0], srow[1], srow[2], srow[3]);
    }
    if (tid < 64) {  // per-block BN partial sums over 32 n
        float s1 = 0.f, s2 = 0.f;
#pragma unroll 8
        for (int n = 0; n < 32; ++n) {
            float v = su.out[tid][n];
            s1 += v;
            s2 += v * v;
        }
        part[(bid * 64 + tid) * 2 + 0] = s1;
        part[(bid * 64 + tid) * 2 + 1] = s2;
    }
}

// K3: reduce 1024 block-partials per channel -> scale/shift (deterministic)
__global__ void k_bnstats(const float* __restrict__ part, const float* __restrict__ gamma,
                          const float* __restrict__ beta, float* __restrict__ stats) {
    int o = blockIdx.x;
    int tid = threadIdx.x;
    __shared__ float s1s[256], s2s[256];
    float s1 = 0.f, s2 = 0.f;
    for (int j = tid; j < 1024; j += 256) {
        s1 += part[(j * 64 + o) * 2 + 0];
        s2 += part[(j * 64 + o) * 2 + 1];
    }
    s1s[tid] = s1;
    s2s[tid] = s2;
    __syncthreads();
    for (int s = 128; s > 0; s >>= 1) {
        if (tid < s) {
            s1s[tid] += s1s[tid + s];
            s2s[tid] += s2s[tid + s];
        }
        __syncthreads();
    }
    if (tid == 0) {
        const float cnt = (float)(B_ * N_);
        float mean = s1s[0] / cnt;
        float var = s2s[0] / cnt - mean * mean;
        float sc = gamma[o] * rsqrtf(var + BN_EPS);
        stats[o * 2 + 0] = sc;
        stats[o * 2 + 1] = beta[o] - mean * sc;
    }
}

// K4: normalize + ReLU, float4
__global__ void k_finalize(const float* __restrict__ raw, const float* __restrict__ stats,
                           float* __restrict__ out) {
    int e = (blockIdx.x * 256 + threadIdx.x) * 4;
    int o = (e >> 12) & 63;
    float sc = stats[o * 2 + 0], sh = stats[o * 2 + 1];
    float4 v = *(const float4*)(raw + e);
    v.x = fmaxf(v.x * sc + sh, 0.f);
    v.y = fmaxf(v.y * sc + sh, 0.f);
    v.z = fmaxf(v.z * sc + sh, 0.f);
    v.w = fmaxf(v.w * sc + sh, 0.f);
    *(float4*)(out + e) = v;
}

extern "C" void kernel_launch(void* const* d_in, const int* in_sizes, int n_in,
                              void* d_out, int out_size, void* d_ws, size_t ws_size,
                              hipStream_t stream) {
    const float* feat = (const float*)d_in[0];
    const int* idx = (const int*)d_in[1];
    const float* gpc = (const float*)d_in[2];
    const float* weights = (const float*)d_in[3];
    const float* conv_w = (const float*)d_in[4];
    const float* gamma = (const float*)d_in[5];
    const float* beta = (const float*)d_in[6];
    float* out = (float*)d_out;
    float* ws = (float*)d_ws;

    float* featT = ws + WS_FEATT;
    _Float16* Wh = (_Float16*)(ws + WS_WT);
    float* raw = ws + WS_RAW;
    float* part = ws + WS_PART;
    float* stats = ws + WS_STATS;

    hipLaunchKernelGGL(k_transpose_feat, dim3(512), dim3(256), 0, stream, feat, featT);
    hipLaunchKernelGGL(k_pack_w, dim3((K_ * T_ * C_ * O_) / 256), dim3(256), 0, stream, conv_w,
                       Wh);
    hipLaunchKernelGGL(k_main, dim3(B_ * (N_ / 32)), dim3(512), 0, stream, featT, Wh, weights,
                       gpc, idx, raw, part);
    hipLaunchKernelGGL(k_bnstats, dim3(O_), dim3(256), 0, stream, part, gamma, beta, stats);
    hipLaunchKernelGGL(k_finalize, dim3(B_ * O_ * N_ / 4 / 256), dim3(256), 0, stream, raw, stats,
                       out);
}